// Round 2
// baseline (548.451 us; speedup 1.0000x reference)
//
#include <hip/hip_runtime.h>
#include <hip/hip_bf16.h>

#define N_NODES 8192
#define F_IN 512
#define F_OUT 256
#define KSPLIT 4
#define KCHUNK (N_NODES / KSPLIT)

using short8 = __attribute__((ext_vector_type(8))) short;
using f32x4  = __attribute__((ext_vector_type(4))) float;

__device__ __forceinline__ short f2bf(float v) {
    union { float f; unsigned u; } x; x.f = v;
    unsigned r = x.u + 0x7fffu + ((x.u >> 16) & 1u);   // RNE
    return (short)(r >> 16);
}

// A0: w1 = W@a1, w2 = W@a2 (fp32, exact scores via associativity), WTg[c][k] = bf16(W[k][c])
__global__ void k_prep(const float* __restrict__ W, const float* __restrict__ a1,
                       const float* __restrict__ a2, float* __restrict__ w1,
                       float* __restrict__ w2, short* __restrict__ WTg) {
    const int k = blockIdx.x;          // 0..511
    const int l = threadIdx.x;         // 0..63
    float4 wv = *(const float4*)(W + (size_t)k * F_OUT + 4 * l);
    float4 av = *(const float4*)(a1 + 4 * l);
    float4 bv = *(const float4*)(a2 + 4 * l);
    float s1 = wv.x*av.x + wv.y*av.y + wv.z*av.z + wv.w*av.w;
    float s2 = wv.x*bv.x + wv.y*bv.y + wv.z*bv.z + wv.w*bv.w;
    WTg[(size_t)(4*l+0)*F_IN + k] = f2bf(wv.x);
    WTg[(size_t)(4*l+1)*F_IN + k] = f2bf(wv.y);
    WTg[(size_t)(4*l+2)*F_IN + k] = f2bf(wv.z);
    WTg[(size_t)(4*l+3)*F_IN + k] = f2bf(wv.w);
    #pragma unroll
    for (int off = 32; off; off >>= 1) {
        s1 += __shfl_down(s1, off);
        s2 += __shfl_down(s2, off);
    }
    if (l == 0) { w1[k] = s1; w2[k] = s2; }
}

// A1: f1 = x@w1, f2 = x@w2 (one wave per row)
__global__ void k_f12(const float* __restrict__ x, const float* __restrict__ w1,
                      const float* __restrict__ w2, float* __restrict__ f1,
                      float* __restrict__ f2) {
    const int wv = threadIdx.x >> 6, l = threadIdx.x & 63;
    const int i = blockIdx.x * 4 + wv;
    const float* xr = x + (size_t)i * F_IN;
    float s1 = 0.f, s2 = 0.f;
    #pragma unroll
    for (int t = 0; t < 2; ++t) {
        int k = t * 256 + l * 4;
        float4 xv = *(const float4*)(xr + k);
        float4 u  = *(const float4*)(w1 + k);
        float4 v  = *(const float4*)(w2 + k);
        s1 += xv.x*u.x + xv.y*u.y + xv.z*u.z + xv.w*u.w;
        s2 += xv.x*v.x + xv.y*v.y + xv.z*v.z + xv.w*v.w;
    }
    #pragma unroll
    for (int off = 32; off; off >>= 1) {
        s1 += __shfl_down(s1, off);
        s2 += __shfl_down(s2, off);
    }
    if (l == 0) { f1[i] = s1; f2[i] = s2; }
}

// A1b: F2max = max over all f2 (global softmax shift: valid upper bound, softmax is shift-invariant)
__global__ void k_f2max(const float* __restrict__ f2, float* __restrict__ F2max) {
    const int t = threadIdx.x;
    float m = -3.4e38f;
    for (int i = t; i < N_NODES; i += 1024) m = fmaxf(m, f2[i]);
    #pragma unroll
    for (int off = 32; off; off >>= 1) m = fmaxf(m, __shfl_down(m, off));
    __shared__ float sm[16];
    if ((t & 63) == 0) sm[t >> 6] = m;
    __syncthreads();
    if (t == 0) {
        float mm = sm[0];
        #pragma unroll
        for (int w = 1; w < 16; ++w) mm = fmaxf(mm, sm[w]);
        *F2max = mm;
    }
}

// A2: hT[c][i] = bf16( sum_k x[i][k] W[k][c] ), via MFMA; D[m=c][n=i]
__launch_bounds__(256)
__global__ void k_hT(const float* __restrict__ x, const short* __restrict__ WTg,
                     short* __restrict__ hT) {
    __shared__ short x_lds[32 * 64];    // [i][k] 128B rows, chunk^row XOR swizzle
    __shared__ short wt_lds[256 * 64];  // [c][k]
    const int tid = threadIdx.x;
    const int wv = tid >> 6, l = tid & 63, lg = l >> 4, lr = l & 15;
    const int ibase = blockIdx.x * 32;
    f32x4 acc[4][2];
    #pragma unroll
    for (int a = 0; a < 4; ++a)
        #pragma unroll
        for (int b = 0; b < 2; ++b) acc[a][b] = (f32x4){0.f, 0.f, 0.f, 0.f};
    for (int k0 = 0; k0 < F_IN; k0 += 64) {
        __syncthreads();
        {   // stage x tile [32][64] as bf16
            int i = tid >> 3, ch = tid & 7;
            const float* src = x + (size_t)(ibase + i) * F_IN + k0 + ch * 8;
            float4 v0 = *(const float4*)(src);
            float4 v1 = *(const float4*)(src + 4);
            short8 s;
            s[0]=f2bf(v0.x); s[1]=f2bf(v0.y); s[2]=f2bf(v0.z); s[3]=f2bf(v0.w);
            s[4]=f2bf(v1.x); s[5]=f2bf(v1.y); s[6]=f2bf(v1.z); s[7]=f2bf(v1.w);
            *(short8*)&x_lds[i * 64 + 8 * (ch ^ (i & 7))] = s;
        }
        {   // stage WT tile [256][64]
            int cb = tid >> 3, ch = tid & 7;
            #pragma unroll
            for (int p = 0; p < 8; ++p) {
                int c = cb + 32 * p;
                short8 s = *(const short8*)(WTg + (size_t)c * F_IN + k0 + ch * 8);
                *(short8*)&wt_lds[c * 64 + 8 * (ch ^ (c & 7))] = s;
            }
        }
        __syncthreads();
        #pragma unroll
        for (int ks = 0; ks < 2; ++ks) {
            short8 bfrag[2], afrag[4];
            #pragma unroll
            for (int it = 0; it < 2; ++it) {
                int i = it * 16 + lr;
                bfrag[it] = *(short8*)&x_lds[i * 64 + 8 * ((lg + 4*ks) ^ (i & 7))];
            }
            #pragma unroll
            for (int ct = 0; ct < 4; ++ct) {
                int c = wv * 64 + ct * 16 + lr;
                afrag[ct] = *(short8*)&wt_lds[c * 64 + 8 * ((lg + 4*ks) ^ (c & 7))];
            }
            #pragma unroll
            for (int ct = 0; ct < 4; ++ct)
                #pragma unroll
                for (int it = 0; it < 2; ++it)
                    acc[ct][it] = __builtin_amdgcn_mfma_f32_16x16x32_bf16(
                        afrag[ct], bfrag[it], acc[ct][it], 0, 0, 0);
        }
    }
    #pragma unroll
    for (int ct = 0; ct < 4; ++ct)
        #pragma unroll
        for (int it = 0; it < 2; ++it)
            #pragma unroll
            for (int r = 0; r < 4; ++r) {
                int c = wv * 64 + ct * 16 + 4 * lg + r;   // D row = m = c
                int i = ibase + it * 16 + lr;             // D col = n = i
                hT[(size_t)c * N_NODES + i] = f2bf(acc[ct][it][r]);
            }
}

// B: fused masked-softmax(P) + P@h over a K-range; fp32 partial O and row-sum out.
// Adjacency is streamed COALESCED through LDS as a 64x64 bit tile (ballot-free
// nibble pack via 4-lane shfl_xor), replacing the scattered per-lane int4 loads.
__launch_bounds__(256)
__global__ void k_attn(const int* __restrict__ adj, const short* __restrict__ hT,
                       const float* __restrict__ f1, const float* __restrict__ f2,
                       const float* __restrict__ F2maxp, float* __restrict__ part,
                       float* __restrict__ psum) {
    __shared__ short h_lds[256 * 64];          // hT slice [c][k], 128B rows, XOR swizzle
    __shared__ unsigned short am_lds[64 * 4];  // adj bit tile: [row][seg], seg = 16 k-bits
    const int tid = threadIdx.x;
    const int wv = tid >> 6, l = tid & 63, lg = l >> 4, lr = l & 15;
    const int ksid = blockIdx.x >> 7;      // 0..3 (slow index: co-resident blocks share hT slice)
    const int rowblk = blockIdx.x & 127;
    const int r0 = rowblk * 64;
    const int myrow = r0 + wv * 16 + lr;   // A-fragment row for this lane
    // adj staging role: 4 lanes (q) per row, wave covers 16 rows
    const int q = l & 3, srow = wv * 16 + (l >> 2);
    const int* asrc = adj + (size_t)(r0 + srow) * N_NODES;
    const float F2m = *F2maxp;
    const float f1v = f1[myrow];
    const float e0 = f1v + F2m;
    const float cr = fmaxf(e0, 0.2f * e0);     // upper bound of row scores (monotone leaky)
    const float L2E = 1.44269504f;
    const float crl = cr * L2E;
    f32x4 acc[16];
    #pragma unroll
    for (int t = 0; t < 16; ++t) acc[t] = (f32x4){0.f, 0.f, 0.f, 0.f};
    float ps = 0.f;
    const int kbeg = ksid * KCHUNK;
    for (int k0 = kbeg; k0 < kbeg + KCHUNK; k0 += 64) {
        __syncthreads();
        {   // stage hT[0:256][k0:k0+64] -> LDS (coalesced 128B runs)
            int cb = tid >> 3, ch = tid & 7;
            #pragma unroll
            for (int p = 0; p < 8; ++p) {
                int c = cb + 32 * p;
                short8 s = *(const short8*)(hT + (size_t)c * N_NODES + k0 + ch * 8);
                *(short8*)&h_lds[c * 64 + 8 * (ch ^ (c & 7))] = s;
            }
        }
        {   // stage adj[r0:r0+64][k0:k0+64] -> 16-bit seg masks (coalesced 64B runs)
            unsigned mseg[4];
            #pragma unroll
            for (int p = 0; p < 4; ++p) {
                int4 v = *(const int4*)(asrc + k0 + p * 16 + q * 4);
                unsigned nib = (v.x > 0 ? 1u : 0u) | (v.y > 0 ? 2u : 0u) |
                               (v.z > 0 ? 4u : 0u) | (v.w > 0 ? 8u : 0u);
                unsigned m = nib << (4 * q);
                m |= __shfl_xor(m, 1);
                m |= __shfl_xor(m, 2);
                mseg[p] = m;
            }
            am_lds[srow * 4 + q] = (unsigned short)mseg[q];
        }
        __syncthreads();
        #pragma unroll
        for (int ks = 0; ks < 2; ++ks) {
            const int kg = k0 + 32 * ks + 8 * lg;     // this lane's 8-k window
            const unsigned am = am_lds[(wv * 16 + lr) * 4 + 2 * ks + (lg >> 1)];
            const unsigned mbyte = (am >> (8 * (lg & 1))) & 0xffu;
            const float4 fa = *(const float4*)(f2 + kg);
            const float4 fb = *(const float4*)(f2 + kg + 4);
            const float f2v[8] = {fa.x, fa.y, fa.z, fa.w, fb.x, fb.y, fb.z, fb.w};
            short8 pa;
            #pragma unroll
            for (int j = 0; j < 8; ++j) {
                float ee = f1v + f2v[j];
                float le = fmaxf(ee, 0.2f * ee);                       // LeakyReLU
                float pv = (mbyte & (1u << j)) ? exp2f(fmaf(le, L2E, -crl)) : 0.f;
                ps += pv;
                pa[j] = f2bf(pv);
            }
            #pragma unroll
            for (int t = 0; t < 16; ++t) {
                int c = t * 16 + lr;
                short8 bfrag = *(short8*)&h_lds[c * 64 + 8 * ((lg + 4*ks) ^ (c & 7))];
                acc[t] = __builtin_amdgcn_mfma_f32_16x16x32_bf16(pa, bfrag, acc[t], 0, 0, 0);
            }
        }
    }
    ps += __shfl_xor(ps, 16);
    ps += __shfl_xor(ps, 32);
    if (lg == 0) psum[ksid * N_NODES + myrow] = ps;
    float* pb = part + (size_t)ksid * N_NODES * F_OUT;
    #pragma unroll
    for (int t = 0; t < 16; ++t)
        #pragma unroll
        for (int r = 0; r < 4; ++r) {
            int row = r0 + wv * 16 + 4 * lg + r;   // D row = 4*(lane>>4)+reg
            int c = t * 16 + lr;                   // D col = lane&15
            pb[(size_t)row * F_OUT + c] = acc[t][r];
        }
}

// C: out = ELU( (sum_s part) / (sum_s psum) )
__global__ void k_comb(const float* __restrict__ part, const float* __restrict__ psum,
                       float* __restrict__ out) {
    const int i = blockIdx.x, c = threadIdx.x;
    float o = 0.f, s = 0.f;
    #pragma unroll
    for (int q = 0; q < KSPLIT; ++q) {
        o += part[(size_t)q * N_NODES * F_OUT + (size_t)i * F_OUT + c];
        s += psum[q * N_NODES + i];
    }
    float v = o / s;
    out[(size_t)i * F_OUT + c] = (v > 0.f) ? v : expm1f(v);
}

extern "C" void kernel_launch(void* const* d_in, const int* in_sizes, int n_in,
                              void* d_out, int out_size, void* d_ws, size_t ws_size,
                              hipStream_t stream) {
    const float* x  = (const float*)d_in[0];
    const int* adj  = (const int*)d_in[1];
    const float* W  = (const float*)d_in[2];
    const float* a1 = (const float*)d_in[3];
    const float* a2 = (const float*)d_in[4];
    float* out = (float*)d_out;

    // workspace layout (~36.5 MB)
    short* hT  = (short*)d_ws;                          // [256][8192] bf16
    short* WTg = hT + (size_t)F_OUT * N_NODES;          // [256][512] bf16
    float* fb  = (float*)(WTg + (size_t)F_OUT * F_IN);
    float* w1   = fb;
    float* w2   = fb + 512;
    float* f1   = fb + 1024;
    float* f2   = fb + 1024 + N_NODES;
    float* F2m  = fb + 1024 + 2 * N_NODES;
    float* part = fb + 32768;                           // [4][8192][256] f32
    float* psum = part + (size_t)KSPLIT * N_NODES * F_OUT;  // [4][8192] f32

    k_prep<<<F_IN, 64, 0, stream>>>(W, a1, a2, w1, w2, WTg);
    k_f12<<<N_NODES / 4, 256, 0, stream>>>(x, w1, w2, f1, f2);
    k_f2max<<<1, 1024, 0, stream>>>(f2, F2m);
    k_hT<<<N_NODES / 32, 256, 0, stream>>>(x, WTg, hT);
    k_attn<<<128 * KSPLIT, 256, 0, stream>>>(adj, hT, f1, f2, F2m, part, psum);
    k_comb<<<N_NODES, 256, 0, stream>>>(part, psum, out);
}

// Round 3
// 477.772 us; speedup vs baseline: 1.1479x; 1.1479x over previous
//
#include <hip/hip_runtime.h>
#include <hip/hip_bf16.h>

#define N_NODES 8192
#define F_IN 512
#define F_OUT 256
#define KSPLIT 4
#define KCHUNK (N_NODES / KSPLIT)

using short8 = __attribute__((ext_vector_type(8))) short;
using f32x4  = __attribute__((ext_vector_type(4))) float;

__device__ __forceinline__ short f2bf(float v) {
    union { float f; unsigned u; } x; x.f = v;
    unsigned r = x.u + 0x7fffu + ((x.u >> 16) & 1u);   // RNE
    return (short)(r >> 16);
}

// A0: w1 = W@a1, w2 = W@a2 (fp32, exact scores via associativity), WTg[c][k] = bf16(W[k][c])
__global__ void k_prep(const float* __restrict__ W, const float* __restrict__ a1,
                       const float* __restrict__ a2, float* __restrict__ w1,
                       float* __restrict__ w2, short* __restrict__ WTg) {
    const int k = blockIdx.x;          // 0..511
    const int l = threadIdx.x;         // 0..63
    float4 wv = *(const float4*)(W + (size_t)k * F_OUT + 4 * l);
    float4 av = *(const float4*)(a1 + 4 * l);
    float4 bv = *(const float4*)(a2 + 4 * l);
    float s1 = wv.x*av.x + wv.y*av.y + wv.z*av.z + wv.w*av.w;
    float s2 = wv.x*bv.x + wv.y*bv.y + wv.z*bv.z + wv.w*bv.w;
    WTg[(size_t)(4*l+0)*F_IN + k] = f2bf(wv.x);
    WTg[(size_t)(4*l+1)*F_IN + k] = f2bf(wv.y);
    WTg[(size_t)(4*l+2)*F_IN + k] = f2bf(wv.z);
    WTg[(size_t)(4*l+3)*F_IN + k] = f2bf(wv.w);
    #pragma unroll
    for (int off = 32; off; off >>= 1) {
        s1 += __shfl_down(s1, off);
        s2 += __shfl_down(s2, off);
    }
    if (l == 0) { w1[k] = s1; w2[k] = s2; }
}

// A1: f1 = x@w1, f2 = x@w2 (one wave per row)
__global__ void k_f12(const float* __restrict__ x, const float* __restrict__ w1,
                      const float* __restrict__ w2, float* __restrict__ f1,
                      float* __restrict__ f2) {
    const int wv = threadIdx.x >> 6, l = threadIdx.x & 63;
    const int i = blockIdx.x * 4 + wv;
    const float* xr = x + (size_t)i * F_IN;
    float s1 = 0.f, s2 = 0.f;
    #pragma unroll
    for (int t = 0; t < 2; ++t) {
        int k = t * 256 + l * 4;
        float4 xv = *(const float4*)(xr + k);
        float4 u  = *(const float4*)(w1 + k);
        float4 v  = *(const float4*)(w2 + k);
        s1 += xv.x*u.x + xv.y*u.y + xv.z*u.z + xv.w*u.w;
        s2 += xv.x*v.x + xv.y*v.y + xv.z*v.z + xv.w*v.w;
    }
    #pragma unroll
    for (int off = 32; off; off >>= 1) {
        s1 += __shfl_down(s1, off);
        s2 += __shfl_down(s2, off);
    }
    if (l == 0) { f1[i] = s1; f2[i] = s2; }
}

// A2: hT[c][i] = bf16( sum_k x[i][k] W[k][c] ), via MFMA; D[m=c][n=i]
__launch_bounds__(256)
__global__ void k_hT(const float* __restrict__ x, const short* __restrict__ WTg,
                     short* __restrict__ hT) {
    __shared__ short x_lds[32 * 64];    // [i][k] 128B rows, chunk^row XOR swizzle
    __shared__ short wt_lds[256 * 64];  // [c][k]
    const int tid = threadIdx.x;
    const int wv = tid >> 6, l = tid & 63, lg = l >> 4, lr = l & 15;
    const int ibase = blockIdx.x * 32;
    f32x4 acc[4][2];
    #pragma unroll
    for (int a = 0; a < 4; ++a)
        #pragma unroll
        for (int b = 0; b < 2; ++b) acc[a][b] = (f32x4){0.f, 0.f, 0.f, 0.f};
    for (int k0 = 0; k0 < F_IN; k0 += 64) {
        __syncthreads();
        {   // stage x tile [32][64] as bf16
            int i = tid >> 3, ch = tid & 7;
            const float* src = x + (size_t)(ibase + i) * F_IN + k0 + ch * 8;
            float4 v0 = *(const float4*)(src);
            float4 v1 = *(const float4*)(src + 4);
            short8 s;
            s[0]=f2bf(v0.x); s[1]=f2bf(v0.y); s[2]=f2bf(v0.z); s[3]=f2bf(v0.w);
            s[4]=f2bf(v1.x); s[5]=f2bf(v1.y); s[6]=f2bf(v1.z); s[7]=f2bf(v1.w);
            *(short8*)&x_lds[i * 64 + 8 * (ch ^ (i & 7))] = s;
        }
        {   // stage WT tile [256][64]
            int cb = tid >> 3, ch = tid & 7;
            #pragma unroll
            for (int p = 0; p < 8; ++p) {
                int c = cb + 32 * p;
                short8 s = *(const short8*)(WTg + (size_t)c * F_IN + k0 + ch * 8);
                *(short8*)&wt_lds[c * 64 + 8 * (ch ^ (c & 7))] = s;
            }
        }
        __syncthreads();
        #pragma unroll
        for (int ks = 0; ks < 2; ++ks) {
            short8 bfrag[2], afrag[4];
            #pragma unroll
            for (int it = 0; it < 2; ++it) {
                int i = it * 16 + lr;
                bfrag[it] = *(short8*)&x_lds[i * 64 + 8 * ((lg + 4*ks) ^ (i & 7))];
            }
            #pragma unroll
            for (int ct = 0; ct < 4; ++ct) {
                int c = wv * 64 + ct * 16 + lr;
                afrag[ct] = *(short8*)&wt_lds[c * 64 + 8 * ((lg + 4*ks) ^ (c & 7))];
            }
            #pragma unroll
            for (int ct = 0; ct < 4; ++ct)
                #pragma unroll
                for (int it = 0; it < 2; ++it)
                    acc[ct][it] = __builtin_amdgcn_mfma_f32_16x16x32_bf16(
                        afrag[ct], bfrag[it], acc[ct][it], 0, 0, 0);
        }
    }
    #pragma unroll
    for (int ct = 0; ct < 4; ++ct)
        #pragma unroll
        for (int it = 0; it < 2; ++it)
            #pragma unroll
            for (int r = 0; r < 4; ++r) {
                int c = wv * 64 + ct * 16 + 4 * lg + r;   // D row = m = c
                int i = ibase + it * 16 + lr;             // D col = n = i
                hT[(size_t)c * N_NODES + i] = f2bf(acc[ct][it][r]);
            }
}

// B: fused masked-softmax(P) + P@h over a K-range, register-double-buffered:
// tile t+1's global loads (hT slice + adjacency) are in flight during COMPUTE(t);
// LDS writes happen in a short barrier-bracketed phase with no global latency.
__launch_bounds__(256, 2)
__global__ void k_attn(const int* __restrict__ adj, const short* __restrict__ hT,
                       const float* __restrict__ f1, const float* __restrict__ f2,
                       float* __restrict__ part, float* __restrict__ psum) {
    __shared__ short h_lds[256 * 64];          // hT slice [c][k], 128B rows, XOR swizzle
    __shared__ unsigned short am_lds[64 * 4];  // adj bit tile: [row][seg], seg = 16 k-bits
    const int tid = threadIdx.x;
    const int wv = tid >> 6, l = tid & 63, lg = l >> 4, lr = l & 15;
    const int ksid = blockIdx.x >> 7;      // 0..3 (slow index: co-resident blocks share hT slice)
    const int rowblk = blockIdx.x & 127;
    const int r0 = rowblk * 64;
    const int myrow = r0 + wv * 16 + lr;   // A-fragment row for this lane
    // hT staging role: 8 chunk-columns (ch) x 32-row groups
    const int cb = tid >> 3, ch = tid & 7;
    const short* hsrc = hT + (size_t)cb * N_NODES + ch * 8;
    const int hswz = 8 * (ch ^ (cb & 7));
    // adj staging role: 4 lanes (q) per row; thread owns 16-bit segment q of its row
    const int q = l & 3, srow = wv * 16 + (l >> 2);
    const int* asrc = adj + (size_t)(r0 + srow) * N_NODES + q * 16;
    const int srow4 = srow * 4 + q;
    const int rowm4 = (wv * 16 + lr) * 4;
    const float f1v = f1[myrow];
    const float L2E = 1.44269504f;
    f32x4 acc[16];
    #pragma unroll
    for (int t = 0; t < 16; ++t) acc[t] = (f32x4){0.f, 0.f, 0.f, 0.f};
    float ps = 0.f;
    const int kbeg = ksid * KCHUNK;
    const int kend = kbeg + KCHUNK;

    short8 AH[8], BH[8];
    int4   AA[4], BA[4];

#define LOADT(K0, H, A) do {                                                   \
    _Pragma("unroll")                                                          \
    for (int p = 0; p < 8; ++p)                                                \
        H[p] = *(const short8*)(hsrc + (size_t)(32 * p) * N_NODES + (K0));     \
    _Pragma("unroll")                                                          \
    for (int p = 0; p < 4; ++p)                                                \
        A[p] = *(const int4*)(asrc + (K0) + p * 4);                            \
} while (0)

#define WRITET(H, A) do {                                                      \
    _Pragma("unroll")                                                          \
    for (int p = 0; p < 8; ++p)                                                \
        *(short8*)&h_lds[(cb + 32 * p) * 64 + hswz] = H[p];                    \
    unsigned m = 0;                                                            \
    _Pragma("unroll")                                                          \
    for (int p = 0; p < 4; ++p) {                                              \
        m |= (A[p].x > 0 ? 1u : 0u) << (4 * p);                                \
        m |= (A[p].y > 0 ? 2u : 0u) << (4 * p);                                \
        m |= (A[p].z > 0 ? 4u : 0u) << (4 * p);                                \
        m |= (A[p].w > 0 ? 8u : 0u) << (4 * p);                                \
    }                                                                          \
    am_lds[srow4] = (unsigned short)m;                                         \
} while (0)

#define COMPUTE(K0) do {                                                       \
    _Pragma("unroll")                                                          \
    for (int ks = 0; ks < 2; ++ks) {                                           \
        const int kg = (K0) + 32 * ks + 8 * lg;                                \
        const unsigned am = am_lds[rowm4 + 2 * ks + (lg >> 1)];                \
        const unsigned mbyte = (am >> (8 * (lg & 1))) & 0xffu;                 \
        const float4 fa = *(const float4*)(f2 + kg);                           \
        const float4 fb = *(const float4*)(f2 + kg + 4);                       \
        const float f2v[8] = {fa.x, fa.y, fa.z, fa.w, fb.x, fb.y, fb.z, fb.w}; \
        short8 pa;                                                             \
        _Pragma("unroll")                                                      \
        for (int j = 0; j < 8; ++j) {                                          \
            float ee = f1v + f2v[j];                                           \
            float le = fmaxf(ee, 0.2f * ee);                                   \
            float pv = (mbyte & (1u << j))                                     \
                           ? exp2f(fminf(le * L2E, 80.f)) : 0.f;               \
            ps += pv;                                                          \
            pa[j] = f2bf(pv);                                                  \
        }                                                                      \
        _Pragma("unroll")                                                      \
        for (int t = 0; t < 16; ++t) {                                         \
            const int c = t * 16 + lr;                                         \
            short8 bfrag = *(short8*)&h_lds[c * 64 + 8 * ((lg + 4*ks) ^ (lr & 7))]; \
            acc[t] = __builtin_amdgcn_mfma_f32_16x16x32_bf16(pa, bfrag, acc[t], 0, 0, 0); \
        }                                                                      \
    }                                                                          \
} while (0)

    LOADT(kbeg, AH, AA);
    for (int k0 = kbeg; k0 < kend; k0 += 128) {
        __syncthreads();
        WRITET(AH, AA);
        __syncthreads();
        LOADT(k0 + 64, BH, BA);
        COMPUTE(k0);
        __syncthreads();
        WRITET(BH, BA);
        __syncthreads();
        {
            const int kn = (k0 + 128 < kend) ? (k0 + 128) : kbeg;
            LOADT(kn, AH, AA);
        }
        COMPUTE(k0 + 64);
    }
#undef LOADT
#undef WRITET
#undef COMPUTE

    ps += __shfl_xor(ps, 16);
    ps += __shfl_xor(ps, 32);
    if (lg == 0) psum[ksid * N_NODES + myrow] = ps;
    float* pb = part + (size_t)ksid * N_NODES * F_OUT;
    #pragma unroll
    for (int t = 0; t < 16; ++t)
        #pragma unroll
        for (int r = 0; r < 4; ++r) {
            int row = r0 + wv * 16 + 4 * lg + r;   // D row = 4*(lane>>4)+reg
            int c = t * 16 + lr;                   // D col = lane&15
            pb[(size_t)row * F_OUT + c] = acc[t][r];
        }
}

// C: out = ELU( (sum_s part) / (sum_s psum) )
__global__ void k_comb(const float* __restrict__ part, const float* __restrict__ psum,
                       float* __restrict__ out) {
    const int i = blockIdx.x, c = threadIdx.x;
    float o = 0.f, s = 0.f;
    #pragma unroll
    for (int qq = 0; qq < KSPLIT; ++qq) {
        o += part[(size_t)qq * N_NODES * F_OUT + (size_t)i * F_OUT + c];
        s += psum[qq * N_NODES + i];
    }
    float v = o / s;
    out[(size_t)i * F_OUT + c] = (v > 0.f) ? v : expm1f(v);
}

extern "C" void kernel_launch(void* const* d_in, const int* in_sizes, int n_in,
                              void* d_out, int out_size, void* d_ws, size_t ws_size,
                              hipStream_t stream) {
    const float* x  = (const float*)d_in[0];
    const int* adj  = (const int*)d_in[1];
    const float* W  = (const float*)d_in[2];
    const float* a1 = (const float*)d_in[3];
    const float* a2 = (const float*)d_in[4];
    float* out = (float*)d_out;

    // workspace layout (~36.5 MB)
    short* hT  = (short*)d_ws;                          // [256][8192] bf16
    short* WTg = hT + (size_t)F_OUT * N_NODES;          // [256][512] bf16
    float* fb  = (float*)(WTg + (size_t)F_OUT * F_IN);
    float* w1   = fb;
    float* w2   = fb + 512;
    float* f1   = fb + 1024;
    float* f2   = fb + 1024 + N_NODES;
    float* part = fb + 32768;                           // [4][8192][256] f32
    float* psum = part + (size_t)KSPLIT * N_NODES * F_OUT;  // [4][8192] f32

    k_prep<<<F_IN, 64, 0, stream>>>(W, a1, a2, w1, w2, WTg);
    k_f12<<<N_NODES / 4, 256, 0, stream>>>(x, w1, w2, f1, f2);
    k_hT<<<N_NODES / 32, 256, 0, stream>>>(x, WTg, hT);
    k_attn<<<128 * KSPLIT, 256, 0, stream>>>(adj, hT, f1, f2, part, psum);
    k_comb<<<N_NODES, 256, 0, stream>>>(part, psum, out);
}

// Round 5
// 448.874 us; speedup vs baseline: 1.2218x; 1.0644x over previous
//
#include <hip/hip_runtime.h>
#include <hip/hip_bf16.h>

#define N_NODES 8192
#define F_IN 512
#define F_OUT 256
#define KSPLIT 4
#define KCHUNK (N_NODES / KSPLIT)

using short8 = __attribute__((ext_vector_type(8))) short;
using f32x4  = __attribute__((ext_vector_type(4))) float;

typedef __attribute__((address_space(3))) void lds_t;
typedef const __attribute__((address_space(1))) void gbl_t;

__device__ __forceinline__ short f2bf(float v) {
    union { float f; unsigned u; } x; x.f = v;
    unsigned r = x.u + 0x7fffu + ((x.u >> 16) & 1u);   // RNE
    return (short)(r >> 16);
}

// A0: w1 = W@a1, w2 = W@a2 (fp32, exact scores via associativity), WTg[c][k] = bf16(W[k][c])
__global__ void k_prep(const float* __restrict__ W, const float* __restrict__ a1,
                       const float* __restrict__ a2, float* __restrict__ w1,
                       float* __restrict__ w2, short* __restrict__ WTg) {
    const int k = blockIdx.x;          // 0..511
    const int l = threadIdx.x;         // 0..63
    float4 wv = *(const float4*)(W + (size_t)k * F_OUT + 4 * l);
    float4 av = *(const float4*)(a1 + 4 * l);
    float4 bv = *(const float4*)(a2 + 4 * l);
    float s1 = wv.x*av.x + wv.y*av.y + wv.z*av.z + wv.w*av.w;
    float s2 = wv.x*bv.x + wv.y*bv.y + wv.z*bv.z + wv.w*bv.w;
    WTg[(size_t)(4*l+0)*F_IN + k] = f2bf(wv.x);
    WTg[(size_t)(4*l+1)*F_IN + k] = f2bf(wv.y);
    WTg[(size_t)(4*l+2)*F_IN + k] = f2bf(wv.z);
    WTg[(size_t)(4*l+3)*F_IN + k] = f2bf(wv.w);
    #pragma unroll
    for (int off = 32; off; off >>= 1) {
        s1 += __shfl_down(s1, off);
        s2 += __shfl_down(s2, off);
    }
    if (l == 0) { w1[k] = s1; w2[k] = s2; }
}

// A1: f1 = x@w1, f2 = x@w2 (one wave per row)
__global__ void k_f12(const float* __restrict__ x, const float* __restrict__ w1,
                      const float* __restrict__ w2, float* __restrict__ f1,
                      float* __restrict__ f2) {
    const int wv = threadIdx.x >> 6, l = threadIdx.x & 63;
    const int i = blockIdx.x * 4 + wv;
    const float* xr = x + (size_t)i * F_IN;
    float s1 = 0.f, s2 = 0.f;
    #pragma unroll
    for (int t = 0; t < 2; ++t) {
        int k = t * 256 + l * 4;
        float4 xv = *(const float4*)(xr + k);
        float4 u  = *(const float4*)(w1 + k);
        float4 v  = *(const float4*)(w2 + k);
        s1 += xv.x*u.x + xv.y*u.y + xv.z*u.z + xv.w*u.w;
        s2 += xv.x*v.x + xv.y*v.y + xv.z*v.z + xv.w*v.w;
    }
    #pragma unroll
    for (int off = 32; off; off >>= 1) {
        s1 += __shfl_down(s1, off);
        s2 += __shfl_down(s2, off);
    }
    if (l == 0) { f1[i] = s1; f2[i] = s2; }
}

// A2: hT (pre-swizzled): hTs[c][iswz] = bf16(h[i][c]); within each 64-col block,
// chunk bits (3..5 of i) are XORed with (c&7) so that a LINEAR global_load_lds
// into LDS yields the bank-conflict-free swizzled image (rule #21: src-perm == read-perm).
__launch_bounds__(256)
__global__ void k_hT(const float* __restrict__ x, const short* __restrict__ WTg,
                     short* __restrict__ hTs) {
    __shared__ short x_lds[32 * 64];    // [i][k] 128B rows, chunk^row XOR swizzle
    __shared__ short wt_lds[256 * 64];  // [c][k]
    const int tid = threadIdx.x;
    const int wv = tid >> 6, l = tid & 63, lg = l >> 4, lr = l & 15;
    const int ibase = blockIdx.x * 32;
    f32x4 acc[4][2];
    #pragma unroll
    for (int a = 0; a < 4; ++a)
        #pragma unroll
        for (int b = 0; b < 2; ++b) acc[a][b] = (f32x4){0.f, 0.f, 0.f, 0.f};
    for (int k0 = 0; k0 < F_IN; k0 += 64) {
        __syncthreads();
        {   // stage x tile [32][64] as bf16
            int i = tid >> 3, ch = tid & 7;
            const float* src = x + (size_t)(ibase + i) * F_IN + k0 + ch * 8;
            float4 v0 = *(const float4*)(src);
            float4 v1 = *(const float4*)(src + 4);
            short8 s;
            s[0]=f2bf(v0.x); s[1]=f2bf(v0.y); s[2]=f2bf(v0.z); s[3]=f2bf(v0.w);
            s[4]=f2bf(v1.x); s[5]=f2bf(v1.y); s[6]=f2bf(v1.z); s[7]=f2bf(v1.w);
            *(short8*)&x_lds[i * 64 + 8 * (ch ^ (i & 7))] = s;
        }
        {   // stage WT tile [256][64]
            int cb = tid >> 3, ch = tid & 7;
            #pragma unroll
            for (int p = 0; p < 8; ++p) {
                int c = cb + 32 * p;
                short8 s = *(const short8*)(WTg + (size_t)c * F_IN + k0 + ch * 8);
                *(short8*)&wt_lds[c * 64 + 8 * (ch ^ (c & 7))] = s;
            }
        }
        __syncthreads();
        #pragma unroll
        for (int ks = 0; ks < 2; ++ks) {
            short8 bfrag[2], afrag[4];
            #pragma unroll
            for (int it = 0; it < 2; ++it) {
                int i = it * 16 + lr;
                bfrag[it] = *(short8*)&x_lds[i * 64 + 8 * ((lg + 4*ks) ^ (i & 7))];
            }
            #pragma unroll
            for (int ct = 0; ct < 4; ++ct) {
                int c = wv * 64 + ct * 16 + lr;
                afrag[ct] = *(short8*)&wt_lds[c * 64 + 8 * ((lg + 4*ks) ^ (c & 7))];
            }
            #pragma unroll
            for (int ct = 0; ct < 4; ++ct)
                #pragma unroll
                for (int it = 0; it < 2; ++it)
                    acc[ct][it] = __builtin_amdgcn_mfma_f32_16x16x32_bf16(
                        afrag[ct], bfrag[it], acc[ct][it], 0, 0, 0);
        }
    }
    #pragma unroll
    for (int ct = 0; ct < 4; ++ct)
        #pragma unroll
        for (int it = 0; it < 2; ++it)
            #pragma unroll
            for (int r = 0; r < 4; ++r) {
                int c = wv * 64 + ct * 16 + 4 * lg + r;   // D row = m = c
                int i = ibase + it * 16 + lr;             // D col = n = i
                int isw = (i & ~56) | ((((i >> 3) & 7) ^ (c & 7)) << 3);
                hTs[(size_t)c * N_NODES + isw] = f2bf(acc[ct][it][r]);
            }
}

// B: fused masked-softmax(P) + P@h over a K-range. 2-phase pipeline:
//  - hT slice staged by global_load_lds (width 16) into double-buffered LDS
//    (linear DMA of pre-swizzled global -> swizzled LDS image)
//  - adjacency: coalesced per-wave row loads into regs, bit-pack, 2x shfl
//    redistribution (no LDS, no extra barrier)
//  - ONE __syncthreads per 64-k tile (compiler's vmcnt(0) drain does the wait)
__launch_bounds__(256, 2)
__global__ void k_attn(const int* __restrict__ adj, const short* __restrict__ hTs,
                       const float* __restrict__ f1, const float* __restrict__ f2,
                       float* __restrict__ part, float* __restrict__ psum) {
    __shared__ short h_lds[2 * 16384];         // 2 x [256][64] bf16, swizzled image
    const int tid = threadIdx.x;
    const int wv = tid >> 6, l = tid & 63, lg = l >> 4, lr = l & 15;
    const int ksid = blockIdx.x & 3;       // fast index: each XCD serves ONE k-slice (L2 locality)
    const int rowblk = blockIdx.x >> 2;
    const int r0 = rowblk * 64;
    const int myrow = r0 + wv * 16 + lr;   // A-fragment row for this lane
    // hT staging role (global_load_lds): thread covers row (tid>>3), chunk (tid&7)
    const short* hsrc = hTs + (size_t)(tid >> 3) * N_NODES + (tid & 7) * 8;
    // adj staging role: 4 lanes (q) per row; thread owns 16-bit segment q of its row
    const int q = l & 3, srow = wv * 16 + (l >> 2);
    const int* asrc = adj + (size_t)(r0 + srow) * N_NODES + q * 16;
    const float f1v = f1[myrow];
    const float L2E = 1.44269504f;
    f32x4 acc[16];
    #pragma unroll
    for (int t = 0; t < 16; ++t) acc[t] = (f32x4){0.f, 0.f, 0.f, 0.f};
    float ps = 0.f;
    const int kbeg = ksid * KCHUNK;
    const int kend = kbeg + KCHUNK;

    int4 AA[4], BA[4];

#define STAGE(BUFOFF, K0) do {                                                  \
    _Pragma("unroll")                                                           \
    for (int p = 0; p < 8; ++p)                                                 \
        __builtin_amdgcn_global_load_lds(                                       \
            (gbl_t*)(hsrc + (size_t)p * 32 * N_NODES + (K0)),                   \
            (lds_t*)&h_lds[(BUFOFF) + p * 2048 + wv * 512], 16, 0, 0);          \
} while (0)

#define ADJLOAD(A, K0) do {                                                     \
    _Pragma("unroll")                                                           \
    for (int p = 0; p < 4; ++p) A[p] = *(const int4*)(asrc + (K0) + p * 4);     \
} while (0)

#define COMPUTE_KS(K0, BUFOFF, AMV, KS) do {                                    \
    const int kg = (K0) + 32 * (KS) + 8 * lg;                                   \
    const unsigned mbyte = ((AMV) >> (8 * (lg & 1))) & 0xffu;                   \
    const float4 fa = *(const float4*)(f2 + kg);                                \
    const float4 fb4 = *(const float4*)(f2 + kg + 4);                           \
    const float f2v[8] = {fa.x, fa.y, fa.z, fa.w, fb4.x, fb4.y, fb4.z, fb4.w};  \
    short8 pa;                                                                  \
    _Pragma("unroll")                                                           \
    for (int j = 0; j < 8; ++j) {                                               \
        float ee = f1v + f2v[j];                                                \
        float le = fmaxf(ee, 0.2f * ee);                                        \
        float pv = (mbyte & (1u << j)) ? exp2f(fminf(le * L2E, 80.f)) : 0.f;    \
        ps += pv;                                                               \
        pa[j] = f2bf(pv);                                                       \
    }                                                                           \
    const int swz = 8 * ((lg + 4 * (KS)) ^ (lr & 7));                           \
    __builtin_amdgcn_s_setprio(1);                                              \
    _Pragma("unroll")                                                           \
    for (int t = 0; t < 16; ++t) {                                              \
        short8 bfrag = *(short8*)&h_lds[(BUFOFF) + t * 1024 + lr * 64 + swz];   \
        acc[t] = __builtin_amdgcn_mfma_f32_16x16x32_bf16(pa, bfrag, acc[t], 0, 0, 0); \
    }                                                                           \
    __builtin_amdgcn_s_setprio(0);                                              \
} while (0)

#define COMPUTE(K0, BUFOFF, A) do {                                             \
    unsigned m = 0;                                                             \
    _Pragma("unroll")                                                           \
    for (int p = 0; p < 4; ++p) {                                               \
        m |= (A[p].x > 0 ? 1u : 0u) << (4 * p);                                 \
        m |= (A[p].y > 0 ? 2u : 0u) << (4 * p);                                 \
        m |= (A[p].z > 0 ? 4u : 0u) << (4 * p);                                 \
        m |= (A[p].w > 0 ? 8u : 0u) << (4 * p);                                 \
    }                                                                           \
    const unsigned am0 = (unsigned)__shfl((int)m, (lr << 2) | (lg >> 1));       \
    const unsigned am1 = (unsigned)__shfl((int)m, (lr << 2) | 2 | (lg >> 1));   \
    COMPUTE_KS(K0, BUFOFF, am0, 0);                                             \
    COMPUTE_KS(K0, BUFOFF, am1, 1);                                             \
} while (0)

    STAGE(0, kbeg);
    ADJLOAD(AA, kbeg);
    __syncthreads();                       // vmcnt(0) drain: tile 0 ready
    for (int k0 = kbeg; k0 < kend; k0 += 128) {
        STAGE(16384, k0 + 64);             // fill bufB while computing bufA
        ADJLOAD(BA, k0 + 64);
        COMPUTE(k0, 0, AA);
        __syncthreads();
        if (k0 + 128 < kend) {             // fill bufA while computing bufB
            STAGE(0, k0 + 128);
            ADJLOAD(AA, k0 + 128);
        }
        COMPUTE(k0 + 64, 16384, BA);
        __syncthreads();
    }
#undef STAGE
#undef ADJLOAD
#undef COMPUTE
#undef COMPUTE_KS

    ps += __shfl_xor(ps, 16);
    ps += __shfl_xor(ps, 32);
    if (lg == 0) psum[ksid * N_NODES + myrow] = ps;
    float* pb = part + (size_t)ksid * N_NODES * F_OUT;
    #pragma unroll
    for (int t = 0; t < 16; ++t)
        #pragma unroll
        for (int r = 0; r < 4; ++r) {
            int row = r0 + wv * 16 + 4 * lg + r;   // D row = 4*(lane>>4)+reg
            int c = t * 16 + lr;                   // D col = lane&15
            pb[(size_t)row * F_OUT + c] = acc[t][r];
        }
}

// C: out = ELU( (sum_s part) / (sum_s psum) )
__global__ void k_comb(const float* __restrict__ part, const float* __restrict__ psum,
                       float* __restrict__ out) {
    const int i = blockIdx.x, c = threadIdx.x;
    float o = 0.f, s = 0.f;
    #pragma unroll
    for (int qq = 0; qq < KSPLIT; ++qq) {
        o += part[(size_t)qq * N_NODES * F_OUT + (size_t)i * F_OUT + c];
        s += psum[qq * N_NODES + i];
    }
    float v = o / s;
    out[(size_t)i * F_OUT + c] = (v > 0.f) ? v : expm1f(v);
}

extern "C" void kernel_launch(void* const* d_in, const int* in_sizes, int n_in,
                              void* d_out, int out_size, void* d_ws, size_t ws_size,
                              hipStream_t stream) {
    const float* x  = (const float*)d_in[0];
    const int* adj  = (const int*)d_in[1];
    const float* W  = (const float*)d_in[2];
    const float* a1 = (const float*)d_in[3];
    const float* a2 = (const float*)d_in[4];
    float* out = (float*)d_out;

    // workspace layout (~36.5 MB)
    short* hTs = (short*)d_ws;                          // [256][8192] bf16, pre-swizzled
    short* WTg = hTs + (size_t)F_OUT * N_NODES;         // [256][512] bf16
    float* fb  = (float*)(WTg + (size_t)F_OUT * F_IN);
    float* w1   = fb;
    float* w2   = fb + 512;
    float* f1   = fb + 1024;
    float* f2   = fb + 1024 + N_NODES;
    float* part = fb + 32768;                           // [4][8192][256] f32
    float* psum = part + (size_t)KSPLIT * N_NODES * F_OUT;  // [4][8192] f32

    k_prep<<<F_IN, 64, 0, stream>>>(W, a1, a2, w1, w2, WTg);
    k_f12<<<N_NODES / 4, 256, 0, stream>>>(x, w1, w2, f1, f2);
    k_hT<<<N_NODES / 32, 256, 0, stream>>>(x, WTg, hTs);
    k_attn<<<128 * KSPLIT, 256, 0, stream>>>(adj, hTs, f1, f2, part, psum);
    k_comb<<<N_NODES, 256, 0, stream>>>(part, psum, out);
}

// Round 6
// 437.932 us; speedup vs baseline: 1.2524x; 1.0250x over previous
//
#include <hip/hip_runtime.h>
#include <hip/hip_bf16.h>

#define N_NODES 8192
#define F_IN 512
#define F_OUT 256
#define KSPLIT 4
#define KCHUNK (N_NODES / KSPLIT)
#define NTILES (KCHUNK / 32)   // 64 tiles of 32 k per block

using short8 = __attribute__((ext_vector_type(8))) short;
using f32x4  = __attribute__((ext_vector_type(4))) float;

typedef __attribute__((address_space(3))) void lds_t;
typedef const __attribute__((address_space(1))) void gbl_t;

__device__ __forceinline__ short f2bf(float v) {
    union { float f; unsigned u; } x; x.f = v;
    unsigned r = x.u + 0x7fffu + ((x.u >> 16) & 1u);   // RNE
    return (short)(r >> 16);
}

// A0: w1 = W@a1, w2 = W@a2 (fp32, exact scores via associativity), WTg[c][k] = bf16(W[k][c])
__global__ void k_prep(const float* __restrict__ W, const float* __restrict__ a1,
                       const float* __restrict__ a2, float* __restrict__ w1,
                       float* __restrict__ w2, short* __restrict__ WTg) {
    const int k = blockIdx.x;          // 0..511
    const int l = threadIdx.x;         // 0..63
    float4 wv = *(const float4*)(W + (size_t)k * F_OUT + 4 * l);
    float4 av = *(const float4*)(a1 + 4 * l);
    float4 bv = *(const float4*)(a2 + 4 * l);
    float s1 = wv.x*av.x + wv.y*av.y + wv.z*av.z + wv.w*av.w;
    float s2 = wv.x*bv.x + wv.y*bv.y + wv.z*bv.z + wv.w*bv.w;
    WTg[(size_t)(4*l+0)*F_IN + k] = f2bf(wv.x);
    WTg[(size_t)(4*l+1)*F_IN + k] = f2bf(wv.y);
    WTg[(size_t)(4*l+2)*F_IN + k] = f2bf(wv.z);
    WTg[(size_t)(4*l+3)*F_IN + k] = f2bf(wv.w);
    #pragma unroll
    for (int off = 32; off; off >>= 1) {
        s1 += __shfl_down(s1, off);
        s2 += __shfl_down(s2, off);
    }
    if (l == 0) { w1[k] = s1; w2[k] = s2; }
}

// A1: f1 = x@w1, f2 = x@w2 (one wave per row)
__global__ void k_f12(const float* __restrict__ x, const float* __restrict__ w1,
                      const float* __restrict__ w2, float* __restrict__ f1,
                      float* __restrict__ f2) {
    const int wv = threadIdx.x >> 6, l = threadIdx.x & 63;
    const int i = blockIdx.x * 4 + wv;
    const float* xr = x + (size_t)i * F_IN;
    float s1 = 0.f, s2 = 0.f;
    #pragma unroll
    for (int t = 0; t < 2; ++t) {
        int k = t * 256 + l * 4;
        float4 xv = *(const float4*)(xr + k);
        float4 u  = *(const float4*)(w1 + k);
        float4 v  = *(const float4*)(w2 + k);
        s1 += xv.x*u.x + xv.y*u.y + xv.z*u.z + xv.w*u.w;
        s2 += xv.x*v.x + xv.y*v.y + xv.z*v.z + xv.w*v.w;
    }
    #pragma unroll
    for (int off = 32; off; off >>= 1) {
        s1 += __shfl_down(s1, off);
        s2 += __shfl_down(s2, off);
    }
    if (l == 0) { f1[i] = s1; f2[i] = s2; }
}

// A2: hT[c][i] = bf16( sum_k x[i][k] W[k][c] ), LINEAR layout (swizzle now applied
// at k_attn stage time via per-lane global source addresses).
__launch_bounds__(256)
__global__ void k_hT(const float* __restrict__ x, const short* __restrict__ WTg,
                     short* __restrict__ hT) {
    __shared__ short x_lds[32 * 64];    // [i][k] 128B rows, chunk^row XOR swizzle
    __shared__ short wt_lds[256 * 64];  // [c][k]
    const int tid = threadIdx.x;
    const int wv = tid >> 6, l = tid & 63, lg = l >> 4, lr = l & 15;
    const int ibase = blockIdx.x * 32;
    f32x4 acc[4][2];
    #pragma unroll
    for (int a = 0; a < 4; ++a)
        #pragma unroll
        for (int b = 0; b < 2; ++b) acc[a][b] = (f32x4){0.f, 0.f, 0.f, 0.f};
    for (int k0 = 0; k0 < F_IN; k0 += 64) {
        __syncthreads();
        {   // stage x tile [32][64] as bf16
            int i = tid >> 3, ch = tid & 7;
            const float* src = x + (size_t)(ibase + i) * F_IN + k0 + ch * 8;
            float4 v0 = *(const float4*)(src);
            float4 v1 = *(const float4*)(src + 4);
            short8 s;
            s[0]=f2bf(v0.x); s[1]=f2bf(v0.y); s[2]=f2bf(v0.z); s[3]=f2bf(v0.w);
            s[4]=f2bf(v1.x); s[5]=f2bf(v1.y); s[6]=f2bf(v1.z); s[7]=f2bf(v1.w);
            *(short8*)&x_lds[i * 64 + 8 * (ch ^ (i & 7))] = s;
        }
        {   // stage WT tile [256][64]
            int cb = tid >> 3, ch = tid & 7;
            #pragma unroll
            for (int p = 0; p < 8; ++p) {
                int c = cb + 32 * p;
                short8 s = *(const short8*)(WTg + (size_t)c * F_IN + k0 + ch * 8);
                *(short8*)&wt_lds[c * 64 + 8 * (ch ^ (c & 7))] = s;
            }
        }
        __syncthreads();
        #pragma unroll
        for (int ks = 0; ks < 2; ++ks) {
            short8 bfrag[2], afrag[4];
            #pragma unroll
            for (int it = 0; it < 2; ++it) {
                int i = it * 16 + lr;
                bfrag[it] = *(short8*)&x_lds[i * 64 + 8 * ((lg + 4*ks) ^ (i & 7))];
            }
            #pragma unroll
            for (int ct = 0; ct < 4; ++ct) {
                int c = wv * 64 + ct * 16 + lr;
                afrag[ct] = *(short8*)&wt_lds[c * 64 + 8 * ((lg + 4*ks) ^ (c & 7))];
            }
            #pragma unroll
            for (int ct = 0; ct < 4; ++ct)
                #pragma unroll
                for (int it = 0; it < 2; ++it)
                    acc[ct][it] = __builtin_amdgcn_mfma_f32_16x16x32_bf16(
                        afrag[ct], bfrag[it], acc[ct][it], 0, 0, 0);
        }
    }
    #pragma unroll
    for (int ct = 0; ct < 4; ++ct)
        #pragma unroll
        for (int it = 0; it < 2; ++it)
            #pragma unroll
            for (int r = 0; r < 4; ++r) {
                int c = wv * 64 + ct * 16 + 4 * lg + r;   // D row = m = c
                int i = ibase + it * 16 + lr;             // D col = n = i
                hT[(size_t)c * N_NODES + i] = f2bf(acc[ct][it][r]);
            }
}

// B: fused masked-softmax(P) + P@h, 4-deep LDS pipeline with COUNTED vmcnt:
//  - hT tiles (256 rows x 32 k) staged 2 ahead via global_load_lds into 4 LDS bufs,
//    swizzled via pre-swizzled per-lane GLOBAL source (linear LDS dest)
//  - adjacency prefetched 4 tiles ahead in 4 register sets; packed+shfl'd 1 ahead
//  - per tile: s_waitcnt vmcnt(12) (= 2 iterations in flight) + raw s_barrier
//  - f2 slice lives in LDS: loop vmem count is static (2 adj + 4 stage = 6/iter)
__launch_bounds__(256, 2)
__global__ void k_attn(const int* __restrict__ adj, const short* __restrict__ hT,
                       const float* __restrict__ f1, const float* __restrict__ f2,
                       float* __restrict__ part, float* __restrict__ psum) {
    __shared__ short h_lds[4 * 8192];   // 4 bufs x [256 rows][32 k] bf16 (swizzled image)
    __shared__ float f2_lds[KCHUNK];    // 8 KB
    const int tid = threadIdx.x;
    const int wv = tid >> 6, l = tid & 63, lg = l >> 4, lr = l & 15;
    const int ksid = blockIdx.x & 3;       // per-XCD k-slice (L2 locality)
    const int rowblk = blockIdx.x >> 2;
    const int r0 = rowblk * 64;
    const int myrow = r0 + wv * 16 + lr;
    const int kbeg = ksid * KCHUNK;
    // hT staging: lane covers dest row p*64 + wv*16 + (l>>2), chunk (l&3);
    // source k-chunk pre-swizzled: (l&3) ^ ((l>>3)&3)
    const short* hsrcb = hT + (size_t)(wv * 16 + (l >> 2)) * N_NODES
                            + ((l & 3) ^ ((l >> 3) & 3)) * 8 + kbeg;
    // adj staging: 4 lanes (q=l&3) per row srow, each owns 8 k (one mask byte)
    const int q = l & 3, srow = wv * 16 + (l >> 2);
    const int* asrcb = adj + (size_t)(r0 + srow) * N_NODES + q * 8 + kbeg;
    const float f1v = f1[myrow];
    const float L2E = 1.44269504f;
    const int rdoff = lr * 32 + (lg ^ ((lr >> 1) & 3)) * 8;  // swizzled read base (shorts)
    f32x4 acc[16];
    #pragma unroll
    for (int t = 0; t < 16; ++t) acc[t] = (f32x4){0.f, 0.f, 0.f, 0.f};
    float ps = 0.f;

    int4 S0[2], S1[2], S2[2], S3[2];
    unsigned mA, mB;

#define STAGE(T) do {                                                           \
    _Pragma("unroll")                                                           \
    for (int p = 0; p < 4; ++p)                                                 \
        __builtin_amdgcn_global_load_lds(                                       \
            (gbl_t*)(hsrcb + (size_t)p * 64 * N_NODES + (T) * 32),              \
            (lds_t*)&h_lds[((T) & 3) * 8192 + p * 2048 + wv * 512], 16, 0, 0);  \
} while (0)

#define ADJ(S, T) do {                                                          \
    S[0] = *(const int4*)(asrcb + (T) * 32);                                    \
    S[1] = *(const int4*)(asrcb + (T) * 32 + 4);                                \
} while (0)

#define PACK(MD, S) do {                                                        \
    unsigned _m = (S[0].x > 0 ? 1u : 0u) | (S[0].y > 0 ? 2u : 0u) |             \
                  (S[0].z > 0 ? 4u : 0u) | (S[0].w > 0 ? 8u : 0u) |             \
                  (S[1].x > 0 ? 16u : 0u) | (S[1].y > 0 ? 32u : 0u) |           \
                  (S[1].z > 0 ? 64u : 0u) | (S[1].w > 0 ? 128u : 0u);           \
    MD = (unsigned)__shfl((int)_m, (lr << 2) | lg);                             \
} while (0)

#define COMPUTE(T, MB) do {                                                     \
    const int bo = ((T) & 3) * 8192;                                            \
    const float4 fa = *(const float4*)&f2_lds[(T) * 32 + lg * 8];               \
    const float4 fb4 = *(const float4*)&f2_lds[(T) * 32 + lg * 8 + 4];          \
    const float f2v[8] = {fa.x, fa.y, fa.z, fa.w, fb4.x, fb4.y, fb4.z, fb4.w};  \
    short8 pa;                                                                  \
    _Pragma("unroll")                                                           \
    for (int j = 0; j < 8; ++j) {                                               \
        float ee = f1v + f2v[j];                                                \
        float le = fmaxf(ee, 0.2f * ee);                                        \
        float pv = ((MB) & (1u << j)) ? exp2f(fminf(le * L2E, 80.f)) : 0.f;     \
        ps += pv;                                                               \
        pa[j] = f2bf(pv);                                                       \
    }                                                                           \
    __builtin_amdgcn_s_setprio(1);                                              \
    _Pragma("unroll")                                                           \
    for (int t16 = 0; t16 < 16; ++t16) {                                        \
        short8 bfrag = *(short8*)&h_lds[bo + t16 * 512 + rdoff];                \
        acc[t16] = __builtin_amdgcn_mfma_f32_16x16x32_bf16(pa, bfrag, acc[t16], 0, 0, 0); \
    }                                                                           \
    __builtin_amdgcn_s_setprio(0);                                              \
} while (0)

#define BODY(T, SL, SP, MU, MP) do {                                            \
    PACK(MP, SP);                          /* mask for tile T+1 */              \
    if ((T) + 4 < NTILES) ADJ(SL, (T) + 4);                                     \
    if ((T) + 2 < NTILES) STAGE((T) + 2);                                       \
    asm volatile("s_waitcnt vmcnt(12)" ::: "memory");                           \
    __builtin_amdgcn_s_barrier();                                               \
    __builtin_amdgcn_sched_barrier(0);                                          \
    COMPUTE(T, MU);                                                             \
} while (0)

    // prologue: f2 slice -> LDS; adj tiles 0-3 -> regs; hT tiles 0,1 -> LDS
    {
        int i8 = tid * 8;
        *(float4*)&f2_lds[i8]     = *(const float4*)(f2 + kbeg + i8);
        *(float4*)&f2_lds[i8 + 4] = *(const float4*)(f2 + kbeg + i8 + 4);
    }
    ADJ(S0, 0); ADJ(S1, 1); ADJ(S2, 2); ADJ(S3, 3);
    STAGE(0); STAGE(1);
    PACK(mA, S0);                          // tile 0 mask
    __syncthreads();                       // one-time full drain (tiles 0,1 + f2 ready)

    for (int t = 0; t < NTILES; t += 4) {
        BODY(t + 0, S0, S1, mA, mB);
        BODY(t + 1, S1, S2, mB, mA);
        BODY(t + 2, S2, S3, mA, mB);
        BODY(t + 3, S3, S0, mB, mA);
    }
#undef STAGE
#undef ADJ
#undef PACK
#undef COMPUTE
#undef BODY

    ps += __shfl_xor(ps, 16);
    ps += __shfl_xor(ps, 32);
    if (lg == 0) psum[ksid * N_NODES + myrow] = ps;
    float* pb = part + (size_t)ksid * N_NODES * F_OUT;
    #pragma unroll
    for (int t = 0; t < 16; ++t)
        #pragma unroll
        for (int r = 0; r < 4; ++r) {
            int row = r0 + wv * 16 + 4 * lg + r;   // D row = 4*(lane>>4)+reg
            int c = t * 16 + lr;                   // D col = lane&15
            pb[(size_t)row * F_OUT + c] = acc[t][r];
        }
}

// C: out = ELU( (sum_s part) / (sum_s psum) )
__global__ void k_comb(const float* __restrict__ part, const float* __restrict__ psum,
                       float* __restrict__ out) {
    const int i = blockIdx.x, c = threadIdx.x;
    float o = 0.f, s = 0.f;
    #pragma unroll
    for (int qq = 0; qq < KSPLIT; ++qq) {
        o += part[(size_t)qq * N_NODES * F_OUT + (size_t)i * F_OUT + c];
        s += psum[qq * N_NODES + i];
    }
    float v = o / s;
    out[(size_t)i * F_OUT + c] = (v > 0.f) ? v : expm1f(v);
}

extern "C" void kernel_launch(void* const* d_in, const int* in_sizes, int n_in,
                              void* d_out, int out_size, void* d_ws, size_t ws_size,
                              hipStream_t stream) {
    const float* x  = (const float*)d_in[0];
    const int* adj  = (const int*)d_in[1];
    const float* W  = (const float*)d_in[2];
    const float* a1 = (const float*)d_in[3];
    const float* a2 = (const float*)d_in[4];
    float* out = (float*)d_out;

    // workspace layout (~36.5 MB)
    short* hT  = (short*)d_ws;                          // [256][8192] bf16 (linear)
    short* WTg = hT + (size_t)F_OUT * N_NODES;          // [256][512] bf16
    float* fb  = (float*)(WTg + (size_t)F_OUT * F_IN);
    float* w1   = fb;
    float* w2   = fb + 512;
    float* f1   = fb + 1024;
    float* f2   = fb + 1024 + N_NODES;
    float* part = fb + 32768;                           // [4][8192][256] f32
    float* psum = part + (size_t)KSPLIT * N_NODES * F_OUT;  // [4][8192] f32

    k_prep<<<F_IN, 64, 0, stream>>>(W, a1, a2, w1, w2, WTg);
    k_f12<<<N_NODES / 4, 256, 0, stream>>>(x, w1, w2, f1, f2);
    k_hT<<<N_NODES / 32, 256, 0, stream>>>(x, WTg, hT);
    k_attn<<<128 * KSPLIT, 256, 0, stream>>>(adj, hT, f1, f2, part, psum);
    k_comb<<<N_NODES, 256, 0, stream>>>(part, psum, out);
}